// Round 2
// baseline (1083.010 us; speedup 1.0000x reference)
//
#include <hip/hip_runtime.h>
#include <hip/hip_bf16.h>

typedef float f32x4 __attribute__((ext_vector_type(4)));
typedef short bf16x8 __attribute__((ext_vector_type(8)));

#define NB 50000
#define NK 32
#define NH 128
#define NL 64

__device__ __forceinline__ unsigned short f2bf(float f) {
    unsigned int u = __float_as_uint(f);
    u += 0x7fffu + ((u >> 16) & 1u);
    return (unsigned short)(u >> 16);
}
__device__ __forceinline__ float bf2f(unsigned short u) {
    return __uint_as_float(((unsigned int)u) << 16);
}

__global__ void kl_zero_kernel(float* out) {
    if (threadIdx.x == 0 && blockIdx.x == 0) out[(size_t)NB * NH] = 0.0f;
}

__global__ void __launch_bounds__(256, 1) vibgat_kernel(
    const float* __restrict__ self_feat, const float* __restrict__ neighbor_feat,
    const float* __restrict__ trust_mask, const float* __restrict__ eps,
    const float* __restrict__ pre_g, const float* __restrict__ pre_b,
    const float* __restrict__ W_mu, const float* __restrict__ b_mu,
    const float* __restrict__ W_lv, const float* __restrict__ b_lv,
    const float* __restrict__ post_g, const float* __restrict__ post_b,
    const float* __restrict__ W_q, const float* __restrict__ b_q,
    const float* __restrict__ W_k, const float* __restrict__ b_k,
    const float* __restrict__ W_v, const float* __restrict__ b_v,
    const float* __restrict__ W_o, const float* __restrict__ b_o,
    float* __restrict__ out)
{
    // Per-wave A-tile slice: [32][128] bf16 swizzled (8KB each). z ([32][64] bf16)
    // reuses the first 4KB of the own slice (same-wave LDS ops are in-order).
    __shared__ unsigned short A_lds[4][32 * 128];
    __shared__ unsigned short Wo_lds[64 * 128];     // bf16 row-major [c][h]
    __shared__ float selfl[4][128];
    __shared__ float trustl[4][32];                 // pre-logged
    __shared__ float ctxl[4][64];
    __shared__ float s_preg[128], s_preb[128], s_bo[128];
    __shared__ float s_bmu[64], s_blv[64], s_bq[64], s_bv[64], s_pg[64], s_pb[64];
    __shared__ float klw[4];

    const int t = threadIdx.x;
    const int w = t >> 6;      // wave 0..3
    const int l = t & 63;      // lane
    const int g = l >> 4;      // 16-lane group 0..3
    const int li = l & 15;

    // ---- one-time staging ----
    for (int i = t; i < 64 * 128; i += 256) Wo_lds[i] = f2bf(W_o[i]);
    if (t < 128) { s_preg[t] = pre_g[t]; s_preb[t] = pre_b[t]; s_bo[t] = b_o[t]; }
    if (t < 64)  { s_bmu[t] = b_mu[t]; s_blv[t] = b_lv[t]; s_bq[t] = b_q[t];
                   s_bv[t] = b_v[t];  s_pg[t] = post_g[t]; s_pb[t] = post_b[t]; }

    // ---- persistent weight B-fragments in registers ----
    // B frag (mfma_f32_16x16x32_bf16): col = li + 16*nt, k = 32*s + 8*g + j
    bf16x8 Wml[8][4];   // nt 0..3 = W_mu cols, nt 4..7 = W_lv cols
#pragma unroll
    for (int nt = 0; nt < 8; ++nt) {
        const float* src = (nt < 4) ? W_mu : W_lv;
        int c = li + 16 * (nt & 3);
#pragma unroll
        for (int s = 0; s < 4; ++s) {
            int k0 = 32 * s + 8 * g;
            bf16x8 f;
#pragma unroll
            for (int j = 0; j < 8; ++j) f[j] = (short)f2bf(src[(k0 + j) * 64 + c]);
            Wml[nt][s] = f;
        }
    }
    bf16x8 Wkv[8][2];   // nt 0..3 = W_k, nt 4..7 = W_v
#pragma unroll
    for (int nt = 0; nt < 8; ++nt) {
        const float* src = (nt < 4) ? W_k : W_v;
        int c = li + 16 * (nt & 3);
#pragma unroll
        for (int s = 0; s < 2; ++s) {
            int k0 = 32 * s + 8 * g;
            bf16x8 f;
#pragma unroll
            for (int j = 0; j < 8; ++j) f[j] = (short)f2bf(src[(k0 + j) * 64 + c]);
            Wkv[nt][s] = f;
        }
    }
    bf16x8 Wq[4][4];    // W_q frags (used in VALU dot, every wave)
#pragma unroll
    for (int nt = 0; nt < 4; ++nt) {
        int c = li + 16 * nt;
#pragma unroll
        for (int s = 0; s < 4; ++s) {
            int k0 = 32 * s + 8 * g;
            bf16x8 f;
#pragma unroll
            for (int j = 0; j < 8; ++j) f[j] = (short)f2bf(W_q[(k0 + j) * 64 + c]);
            Wq[nt][s] = f;
        }
    }
    __syncthreads();

    const f32x4 zero4 = {0.f, 0.f, 0.f, 0.f};
    float kl_acc = 0.f;
    unsigned short* myA = &A_lds[w][0];

    for (int b0 = blockIdx.x * 4; b0 < NB; b0 += gridDim.x * 4) {
        const int bn = b0 + w;   // this wave's node (NB % 4 == 0 -> always valid)

        // ---------- P0: eps prefetch (C-layout), trust, self, neighbor LN -> A ----------
        float epr[2][4][4];   // [mt][nt][r] at row=16mt+4g+r, col=li+16nt
        {
            const float* eb = eps + ((size_t)bn * NK + 4 * g) * NL + li;
#pragma unroll
            for (int mt = 0; mt < 2; ++mt)
#pragma unroll
                for (int nt = 0; nt < 4; ++nt)
#pragma unroll
                    for (int r = 0; r < 4; ++r)
                        epr[mt][nt][r] = eb[(size_t)(16 * mt + r) * NL + 16 * nt];
        }
        if (l < 32) trustl[w][l] = __logf(trust_mask[(size_t)bn * NK + l] + 1e-6f);
        {
            float2 sv = ((const float2*)(self_feat + (size_t)bn * NH))[l];
            selfl[w][2 * l] = sv.x; selfl[w][2 * l + 1] = sv.y;
        }
#pragma unroll
        for (int p = 0; p < 2; ++p) {
            const int row = 16 * p + (l >> 2);
            const int c0 = (l & 3) * 32;
            const float* src = neighbor_feat + ((size_t)bn * NK + row) * NH + c0;
            float x[32];
#pragma unroll
            for (int i = 0; i < 8; ++i) {
                float4 v4 = ((const float4*)src)[i];
                x[4 * i] = v4.x; x[4 * i + 1] = v4.y; x[4 * i + 2] = v4.z; x[4 * i + 3] = v4.w;
            }
            float s1 = 0.f;
#pragma unroll
            for (int i = 0; i < 32; ++i) s1 += x[i];
            s1 += __shfl_xor(s1, 1); s1 += __shfl_xor(s1, 2);
            float mean = s1 * (1.f / 128.f);
            float s2 = 0.f;
#pragma unroll
            for (int i = 0; i < 32; ++i) { float d = x[i] - mean; s2 += d * d; }
            s2 += __shfl_xor(s2, 1); s2 += __shfl_xor(s2, 2);
            float inv = rsqrtf(s2 * (1.f / 128.f) + 1e-5f);
#pragma unroll
            for (int u = 0; u < 4; ++u) {
                alignas(16) unsigned short yb[8];
#pragma unroll
                for (int j = 0; j < 8; ++j) {
                    int c = c0 + 8 * u + j;
                    yb[j] = f2bf((x[8 * u + j] - mean) * inv * s_preg[c] + s_preb[c]);
                }
                int boff = row * 256 + (c0 + 8 * u) * 2;
                *(int4*)((char*)myA + (boff ^ ((row & 7) << 4))) = *(int4*)yb;
            }
        }

        // ---------- P1: GEMM1 mu|lv  [32,128]@[128,128] (all nt in this wave) ----------
        f32x4 acc1[2][8];
#pragma unroll
        for (int mt = 0; mt < 2; ++mt)
#pragma unroll
            for (int nt = 0; nt < 8; ++nt) acc1[mt][nt] = zero4;
#pragma unroll
        for (int s = 0; s < 4; ++s) {
            bf16x8 A0 = *(const bf16x8*)((const char*)myA + ((li * 256 + s * 64 + g * 16) ^ ((li & 7) << 4)));
            bf16x8 A1 = *(const bf16x8*)((const char*)myA + (((16 + li) * 256 + s * 64 + g * 16) ^ ((li & 7) << 4)));
#pragma unroll
            for (int nt = 0; nt < 8; ++nt) {
                acc1[0][nt] = __builtin_amdgcn_mfma_f32_16x16x32_bf16(A0, Wml[nt][s], acc1[0][nt], 0, 0, 0);
                acc1[1][nt] = __builtin_amdgcn_mfma_f32_16x16x32_bf16(A1, Wml[nt][s], acc1[1][nt], 0, 0, 0);
            }
        }

        // q[c] = self @ W_q + b_q  (per-lane dot over this group's k's, then cross-group)
        float q4[4];
#pragma unroll
        for (int nt = 0; nt < 4; ++nt) {
            float p = 0.f;
#pragma unroll
            for (int s = 0; s < 4; ++s)
#pragma unroll
                for (int j = 0; j < 8; ++j)
                    p += selfl[w][32 * s + 8 * g + j] * bf2f((unsigned short)Wq[nt][s][j]);
            p += __shfl_xor(p, 16); p += __shfl_xor(p, 32);
            q4[nt] = p + s_bq[li + 16 * nt];
        }

        // ---------- P2: reparam + KL + post-LN, z -> LDS (reuse A slice) ----------
        // overwrite acc1[mt][nt<4][r] with z; lv read from nt+4 first
#pragma unroll
        for (int mt = 0; mt < 2; ++mt)
#pragma unroll
            for (int nt = 0; nt < 4; ++nt)
#pragma unroll
                for (int r = 0; r < 4; ++r) {
                    int c = li + 16 * nt;
                    float mu = acc1[mt][nt][r] + s_bmu[c];
                    float lv = acc1[mt][nt + 4][r] + s_blv[c];
                    float eh = __expf(0.5f * lv);
                    kl_acc += 1.f + lv - mu * mu - eh * eh;
                    acc1[mt][nt][r] = mu + epr[mt][nt][r] * eh;
                }
#pragma unroll
        for (int mt = 0; mt < 2; ++mt)
#pragma unroll
            for (int r = 0; r < 4; ++r) {
                float s1 = acc1[mt][0][r] + acc1[mt][1][r] + acc1[mt][2][r] + acc1[mt][3][r];
                s1 += __shfl_xor(s1, 1); s1 += __shfl_xor(s1, 2);
                s1 += __shfl_xor(s1, 4); s1 += __shfl_xor(s1, 8);
                float mean = s1 * (1.f / 64.f);
                float s2 = 0.f;
#pragma unroll
                for (int nt = 0; nt < 4; ++nt) { float d = acc1[mt][nt][r] - mean; s2 += d * d; }
                s2 += __shfl_xor(s2, 1); s2 += __shfl_xor(s2, 2);
                s2 += __shfl_xor(s2, 4); s2 += __shfl_xor(s2, 8);
                float inv = rsqrtf(s2 * (1.f / 64.f) + 1e-5f);
                int row = 16 * mt + 4 * g + r;
#pragma unroll
                for (int nt = 0; nt < 4; ++nt) {
                    int c = li + 16 * nt;
                    unsigned short zb = f2bf((acc1[mt][nt][r] - mean) * inv * s_pg[c] + s_pb[c]);
                    *(unsigned short*)((char*)myA + ((row * 128 + c * 2) ^ ((row & 7) << 4))) = zb;
                }
            }

        // ---------- P3: k|v GEMM [32,64]@[64,128] + attention (in-register) ----------
        f32x4 acc2[2][8];
#pragma unroll
        for (int mt = 0; mt < 2; ++mt)
#pragma unroll
            for (int nt = 0; nt < 8; ++nt) acc2[mt][nt] = zero4;
#pragma unroll
        for (int s = 0; s < 2; ++s) {
            bf16x8 A0 = *(const bf16x8*)((const char*)myA + ((li * 128 + s * 64 + g * 16) ^ ((li & 7) << 4)));
            bf16x8 A1 = *(const bf16x8*)((const char*)myA + (((16 + li) * 128 + s * 64 + g * 16) ^ ((li & 7) << 4)));
#pragma unroll
            for (int nt = 0; nt < 8; ++nt) {
                acc2[0][nt] = __builtin_amdgcn_mfma_f32_16x16x32_bf16(A0, Wkv[nt][s], acc2[0][nt], 0, 0, 0);
                acc2[1][nt] = __builtin_amdgcn_mfma_f32_16x16x32_bf16(A1, Wkv[nt][s], acc2[1][nt], 0, 0, 0);
            }
        }
        // logits (b_k dropped: constant under softmax); trust pre-logged
        float att[2][4];
#pragma unroll
        for (int mt = 0; mt < 2; ++mt)
#pragma unroll
            for (int r = 0; r < 4; ++r) {
                float p = q4[0] * acc2[mt][0][r] + q4[1] * acc2[mt][1][r]
                        + q4[2] * acc2[mt][2][r] + q4[3] * acc2[mt][3][r];
                p += __shfl_xor(p, 1); p += __shfl_xor(p, 2);
                p += __shfl_xor(p, 4); p += __shfl_xor(p, 8);
                att[mt][r] = p * 0.125f + trustl[w][16 * mt + 4 * g + r];
            }
        float m = att[0][0];
#pragma unroll
        for (int mt = 0; mt < 2; ++mt)
#pragma unroll
            for (int r = 0; r < 4; ++r) m = fmaxf(m, att[mt][r]);
        m = fmaxf(m, __shfl_xor(m, 16)); m = fmaxf(m, __shfl_xor(m, 32));
        float den = 0.f;
#pragma unroll
        for (int mt = 0; mt < 2; ++mt)
#pragma unroll
            for (int r = 0; r < 4; ++r) { att[mt][r] = __expf(att[mt][r] - m); den += att[mt][r]; }
        den += __shfl_xor(den, 16); den += __shfl_xor(den, 32);
        float idn = 1.f / den;
#pragma unroll
        for (int mt = 0; mt < 2; ++mt)
#pragma unroll
            for (int r = 0; r < 4; ++r) att[mt][r] *= idn;
        // context (b_v folded: sum(attn)=1)
#pragma unroll
        for (int nt = 0; nt < 4; ++nt) {
            float cx = 0.f;
#pragma unroll
            for (int mt = 0; mt < 2; ++mt)
#pragma unroll
                for (int r = 0; r < 4; ++r) cx += att[mt][r] * acc2[mt][nt + 4][r];
            cx += __shfl_xor(cx, 16); cx += __shfl_xor(cx, 32);
            if (g == 0) ctxl[w][li + 16 * nt] = cx + s_bv[li + 16 * nt];
        }

        // ---------- P4: comm = ctx @ W_o + b_o  (scalar dot, bf16 Wo from LDS) ----------
        {
            float o0 = 0.f, o1 = 0.f;
#pragma unroll 8
            for (int c = 0; c < 64; ++c) {
                float cv = ctxl[w][c];
                o0 += cv * bf2f(Wo_lds[c * 128 + l]);
                o1 += cv * bf2f(Wo_lds[c * 128 + 64 + l]);
            }
            out[(size_t)bn * NH + l] = o0 + s_bo[l];
            out[(size_t)bn * NH + 64 + l] = o1 + s_bo[64 + l];
        }
    }

    // ---------- KL reduction ----------
#pragma unroll
    for (int msk = 1; msk < 64; msk <<= 1) kl_acc += __shfl_xor(kl_acc, msk);
    if (l == 0) klw[w] = kl_acc;
    __syncthreads();
    if (t == 0) {
        float tot = klw[0] + klw[1] + klw[2] + klw[3];
        atomicAdd(out + (size_t)NB * NH, tot * (-0.5f * 0.001f / ((float)NB * NK)));
    }
}

extern "C" void kernel_launch(void* const* d_in, const int* in_sizes, int n_in,
                              void* d_out, int out_size, void* d_ws, size_t ws_size,
                              hipStream_t stream) {
    const float* self_feat     = (const float*)d_in[0];
    const float* neighbor_feat = (const float*)d_in[1];
    const float* trust_mask    = (const float*)d_in[2];
    const float* eps           = (const float*)d_in[3];
    const float* pre_g  = (const float*)d_in[4];
    const float* pre_b  = (const float*)d_in[5];
    const float* W_mu   = (const float*)d_in[6];
    const float* b_mu   = (const float*)d_in[7];
    const float* W_lv   = (const float*)d_in[8];
    const float* b_lv   = (const float*)d_in[9];
    const float* post_g = (const float*)d_in[10];
    const float* post_b = (const float*)d_in[11];
    const float* W_q    = (const float*)d_in[12];
    const float* b_q    = (const float*)d_in[13];
    const float* W_k    = (const float*)d_in[14];
    const float* b_k    = (const float*)d_in[15];
    const float* W_v    = (const float*)d_in[16];
    const float* b_v    = (const float*)d_in[17];
    const float* W_o    = (const float*)d_in[18];
    const float* b_o    = (const float*)d_in[19];
    float* out = (float*)d_out;
    (void)W_k; (void)b_k;

    hipLaunchKernelGGL(kl_zero_kernel, dim3(1), dim3(64), 0, stream, out);
    hipLaunchKernelGGL(vibgat_kernel, dim3(512), dim3(256), 0, stream,
                       self_feat, neighbor_feat, trust_mask, eps,
                       pre_g, pre_b, W_mu, b_mu, W_lv, b_lv, post_g, post_b,
                       W_q, b_q, W_k, b_k, W_v, b_v, W_o, b_o, out);
}